// Round 1
// baseline (11276.048 us; speedup 1.0000x reference)
//
#include <hip/hip_runtime.h>
#include <hip/hip_bf16.h>

#define BDIM 256

constexpr int TOK = 135;   // J*D tokens
constexpr int KIN = 20;    // DCT input coeffs
constexpr int HID = 256;
constexpr int NFT = 24;    // output DCT coeffs / time steps
constexpr int TTM = 15;    // MLP row tile (9 exact tiles)
constexpr int TTA = 27;    // attention row tile (5 exact tiles)
constexpr int BATCH = 2048;

// ---- LDS layout (bytes) ----
// Qb   : ushort [135][256]                         69120
// Ktb  : ushort [256][135]  (K transposed)         69120
// stag : union region (15360):
//          f32    stag[15][256]  (MLP h1 staging)
//          ushort ats [27][136]  (attn tile, col 135 = zero sentinel)
//          ushort cxs [27][256]  (context tile)
//          ushort hps [27][256]  (p-MLP hidden tile)
// xsb  : ushort [135][20]  (input x)  /  f32 mtab[24][24] after V phase
// o24  : f32 [27][25] (padded, conflict-free idct reads)
// rwl  : f32 [27]     (softmax denominators)
constexpr int OFF_QB   = 0;
constexpr int OFF_KTB  = 69120;
constexpr int OFF_STAG = 138240;
constexpr int OFF_XSB  = 153600;
constexpr int OFF_O24  = 159000;
constexpr int OFF_RWL  = 161700;
constexpr int SMEM_BYTES = 161824;   // <= 163840 (160 KiB/CU)

__device__ __forceinline__ float bfu(unsigned short u) {
  return __uint_as_float(((unsigned int)u) << 16);
}
__device__ __forceinline__ unsigned short f2b(float f) {
  // round-to-nearest-even f32 -> bf16 (inputs are finite)
  unsigned int u = __float_as_uint(f);
  return (unsigned short)((u + 0x7fffu + ((u >> 16) & 1u)) >> 16);
}
__device__ __forceinline__ float pklo(unsigned int p) { return __uint_as_float(p << 16); }
__device__ __forceinline__ float pkhi(unsigned int p) { return __uint_as_float(p & 0xffff0000u); }

// One two-layer MLP over all 135 tokens; thread tid owns output column tid.
// MODE 0: write Q into Qb[t][tid]; MODE 1: write K into Ktb[tid][t];
// MODE 2: write V column into per-thread vv16[t] (scratch, consumed in 4c).
template<int MODE>
__device__ __forceinline__ void mlp_pass(const float* __restrict__ W1, const float* __restrict__ B1,
                                         const float* __restrict__ W2, const float* __restrict__ B2,
                                         const unsigned short* __restrict__ xsb, float* __restrict__ stag,
                                         unsigned short* __restrict__ Qb, unsigned short* __restrict__ Ktb,
                                         unsigned short* __restrict__ vv16, int tid)
{
  float w1c[KIN];
#pragma unroll
  for (int k = 0; k < KIN; ++k) w1c[k] = W1[k * HID + tid];
  const float b1v = B1[tid];
  const float b2v = B2[tid];

  for (int t0 = 0; t0 < TOK; t0 += TTM) {
    // layer 1: h1 = relu(x @ W1 + b1), tile rows t0..t0+14, thread = column
#pragma unroll
    for (int i = 0; i < TTM; ++i) {
      float a = b1v;
      const unsigned short* xr = xsb + (t0 + i) * KIN;
#pragma unroll
      for (int k = 0; k < KIN; ++k) a = fmaf(bfu(xr[k]), w1c[k], a);
      stag[i * HID + tid] = fmaxf(a, 0.0f);
    }
    __syncthreads();

    // layer 2: out = h1 @ W2 + b2 (W2 column streamed from global, L2-resident)
    float acc[TTM];
#pragma unroll
    for (int i = 0; i < TTM; ++i) acc[i] = b2v;
#pragma unroll 2
    for (int c = 0; c < HID; c += 4) {
      const float w0 = W2[(c + 0) * HID + tid];
      const float w1 = W2[(c + 1) * HID + tid];
      const float w2 = W2[(c + 2) * HID + tid];
      const float w3 = W2[(c + 3) * HID + tid];
#pragma unroll
      for (int i = 0; i < TTM; ++i) {
        const float4 s4 = *reinterpret_cast<const float4*>(&stag[i * HID + c]);
        acc[i] = fmaf(s4.x, w0, acc[i]);
        acc[i] = fmaf(s4.y, w1, acc[i]);
        acc[i] = fmaf(s4.z, w2, acc[i]);
        acc[i] = fmaf(s4.w, w3, acc[i]);
      }
    }

    if (MODE == 0) {
#pragma unroll
      for (int i = 0; i < TTM; ++i) Qb[(t0 + i) * HID + tid] = f2b(acc[i]);
    }
    if (MODE == 1) {
#pragma unroll
      for (int i = 0; i < TTM; ++i) Ktb[tid * TOK + (t0 + i)] = f2b(acc[i]);
    }
    if (MODE == 2) {
#pragma unroll
      for (int i = 0; i < TTM; ++i) vv16[t0 + i] = f2b(acc[i]);   // scratch (intentional)
    }
    __syncthreads();
  }
}

__global__ __launch_bounds__(BDIM, 1)
void fused_motion_attn(const float* __restrict__ x,
                       const float* __restrict__ qW1, const float* __restrict__ qb1,
                       const float* __restrict__ qW2, const float* __restrict__ qb2,
                       const float* __restrict__ kW1, const float* __restrict__ kb1,
                       const float* __restrict__ kW2, const float* __restrict__ kb2,
                       const float* __restrict__ vW1, const float* __restrict__ vb1,
                       const float* __restrict__ vW2, const float* __restrict__ vb2,
                       const float* __restrict__ pW1, const float* __restrict__ pb1,
                       const float* __restrict__ pW2, const float* __restrict__ pb2,
                       float* __restrict__ out)
{
  extern __shared__ char smem[];
  unsigned short* Qb   = (unsigned short*)(smem + OFF_QB);
  unsigned short* Ktb  = (unsigned short*)(smem + OFF_KTB);
  float*          stag = (float*)(smem + OFF_STAG);
  unsigned short* ats  = (unsigned short*)(smem + OFF_STAG);
  unsigned short* cxs  = (unsigned short*)(smem + OFF_STAG);
  unsigned short* hps  = (unsigned short*)(smem + OFF_STAG);
  unsigned short* xsb  = (unsigned short*)(smem + OFF_XSB);
  float*          mtab = (float*)(smem + OFF_XSB);
  float*          o24  = (float*)(smem + OFF_O24);
  float*          rwl  = (float*)(smem + OFF_RWL);

  const int tid = threadIdx.x;
  const int b   = blockIdx.x;

  // ---- P0: load x tile (bf16) ----
  const float* xb = x + (size_t)b * (TOK * KIN);
  for (int i = tid; i < TOK * KIN; i += BDIM) xsb[i] = f2b(xb[i]);
  __syncthreads();

  // per-thread V column (runtime-indexed -> scratch; coalesced, latency-hidden)
  union { unsigned int u32[68]; unsigned short u16[136]; } vv;
  vv.u16[135] = 0;   // sentinel pairs with ats[i][135] == 0

  // ---- P1..P3: Q, K, V MLPs ----
  mlp_pass<0>(qW1, qb1, qW2, qb2, xsb, stag, Qb, Ktb, vv.u16, tid);
  mlp_pass<1>(kW1, kb1, kW2, kb2, xsb, stag, Qb, Ktb, vv.u16, tid);
  mlp_pass<2>(vW1, vb1, vW2, vb2, xsb, stag, Qb, Ktb, vv.u16, tid);

  // ---- IDCT basis (overwrites xsb; all xsb reads completed above) ----
  for (int idx = tid; idx < NFT * NFT; idx += BDIM) {
    const int kk = idx / NFT, t = idx - kk * NFT;
    const float c = (kk == 0) ? 0.20412414523193150f : 0.28867513459481287f; // sqrt(1/24), sqrt(2/24)
    mtab[idx] = c * cosf(3.14159265358979323846f * (float)kk * (float)(2 * t + 1) / 48.0f);
  }
  const float pb1v = pb1[tid];
  __syncthreads();

  // ---- P4: attention + projection MLP + IDCT, 5 exact tiles of 27 rows ----
  for (int t0 = 0; t0 < TOK; t0 += TTA) {
    // 4a: scores tile, thread = key index s
    if (tid < TOK) {
      float sc[TTA];
#pragma unroll
      for (int i = 0; i < TTA; ++i) sc[i] = 0.0f;
      for (int h8 = 0; h8 < HID; h8 += 8) {
        float kv[8];
#pragma unroll
        for (int u = 0; u < 8; ++u) kv[u] = bfu(Ktb[(h8 + u) * TOK + tid]);
#pragma unroll
        for (int i = 0; i < TTA; ++i) {
          const uint4 q4 = *reinterpret_cast<const uint4*>(Qb + (t0 + i) * HID + h8);
          sc[i] = fmaf(pklo(q4.x), kv[0], sc[i]);
          sc[i] = fmaf(pkhi(q4.x), kv[1], sc[i]);
          sc[i] = fmaf(pklo(q4.y), kv[2], sc[i]);
          sc[i] = fmaf(pkhi(q4.y), kv[3], sc[i]);
          sc[i] = fmaf(pklo(q4.z), kv[4], sc[i]);
          sc[i] = fmaf(pkhi(q4.z), kv[5], sc[i]);
          sc[i] = fmaf(pklo(q4.w), kv[6], sc[i]);
          sc[i] = fmaf(pkhi(q4.w), kv[7], sc[i]);
        }
      }
#pragma unroll
      for (int i = 0; i < TTA; ++i) ats[i * 136 + tid] = f2b(sc[i] * 0.0625f);
    } else if (tid == TOK) {
#pragma unroll
      for (int i = 0; i < TTA; ++i) ats[i * 136 + TOK] = 0;
    }
    __syncthreads();

    // 4b: row softmax, 8 lanes per row; store unnormalized exp, denom in rwl
    {
      const int g = tid >> 3, j = tid & 7;
      if (g < TTA) {
        float m = -1e30f;
        for (int s = j; s < TOK; s += 8) m = fmaxf(m, bfu(ats[g * 136 + s]));
        m = fmaxf(m, __shfl_xor(m, 1));
        m = fmaxf(m, __shfl_xor(m, 2));
        m = fmaxf(m, __shfl_xor(m, 4));
        float l = 0.0f;
        for (int s = j; s < TOK; s += 8) {
          const float p = __expf(bfu(ats[g * 136 + s]) - m);
          ats[g * 136 + s] = f2b(p);
          l += p;
        }
        l += __shfl_xor(l, 1);
        l += __shfl_xor(l, 2);
        l += __shfl_xor(l, 4);
        if (j == 0) rwl[g] = l;
      }
    }
    __syncthreads();

    // 4c: context tile, thread = value column h (V from per-thread scratch)
    {
      float cacc[TTA];
#pragma unroll
      for (int i = 0; i < TTA; ++i) cacc[i] = 0.0f;
      for (int s2 = 0; s2 < 68; ++s2) {
        const unsigned int vp = vv.u32[s2];
        const float v0 = pklo(vp), v1 = pkhi(vp);
#pragma unroll
        for (int i = 0; i < TTA; ++i) {
          const unsigned int pp = *reinterpret_cast<const unsigned int*>(ats + i * 136 + 2 * s2);
          cacc[i] = fmaf(pklo(pp), v0, cacc[i]);
          cacc[i] = fmaf(pkhi(pp), v1, cacc[i]);
        }
      }
      __syncthreads();   // ats reads complete before overwrite
#pragma unroll
      for (int i = 0; i < TTA; ++i) cxs[i * HID + tid] = f2b(cacc[i] / rwl[i]);
      __syncthreads();
    }

    // 4d: hp = relu([Q, ctx] @ pW1 + pb1), thread = hidden column o
    {
      float hacc[TTA];
#pragma unroll
      for (int i = 0; i < TTA; ++i) hacc[i] = pb1v;
      for (int h8 = 0; h8 < HID; h8 += 8) {           // Q half
        float w[8];
#pragma unroll
        for (int u = 0; u < 8; ++u) w[u] = pW1[(h8 + u) * HID + tid];
#pragma unroll
        for (int i = 0; i < TTA; ++i) {
          const uint4 q4 = *reinterpret_cast<const uint4*>(Qb + (t0 + i) * HID + h8);
          hacc[i] = fmaf(pklo(q4.x), w[0], hacc[i]);
          hacc[i] = fmaf(pkhi(q4.x), w[1], hacc[i]);
          hacc[i] = fmaf(pklo(q4.y), w[2], hacc[i]);
          hacc[i] = fmaf(pkhi(q4.y), w[3], hacc[i]);
          hacc[i] = fmaf(pklo(q4.z), w[4], hacc[i]);
          hacc[i] = fmaf(pkhi(q4.z), w[5], hacc[i]);
          hacc[i] = fmaf(pklo(q4.w), w[6], hacc[i]);
          hacc[i] = fmaf(pkhi(q4.w), w[7], hacc[i]);
        }
      }
      for (int h8 = 0; h8 < HID; h8 += 8) {           // context half
        float w[8];
#pragma unroll
        for (int u = 0; u < 8; ++u) w[u] = pW1[(HID + h8 + u) * HID + tid];
#pragma unroll
        for (int i = 0; i < TTA; ++i) {
          const uint4 c4 = *reinterpret_cast<const uint4*>(cxs + i * HID + h8);
          hacc[i] = fmaf(pklo(c4.x), w[0], hacc[i]);
          hacc[i] = fmaf(pkhi(c4.x), w[1], hacc[i]);
          hacc[i] = fmaf(pklo(c4.y), w[2], hacc[i]);
          hacc[i] = fmaf(pkhi(c4.y), w[3], hacc[i]);
          hacc[i] = fmaf(pklo(c4.z), w[4], hacc[i]);
          hacc[i] = fmaf(pkhi(c4.z), w[5], hacc[i]);
          hacc[i] = fmaf(pklo(c4.w), w[6], hacc[i]);
          hacc[i] = fmaf(pkhi(c4.w), w[7], hacc[i]);
        }
      }
      __syncthreads();   // cxs reads complete before overwrite
#pragma unroll
      for (int i = 0; i < TTA; ++i) hps[i * HID + tid] = f2b(fmaxf(hacc[i], 0.0f));
      __syncthreads();
    }

    // 4e: out24 = hp @ pW2 + pb2  (27x24 outputs per tile)
    for (int idx = tid; idx < TTA * NFT; idx += BDIM) {
      const int i = idx / NFT, f = idx - i * NFT;
      float a = pb2[f];
      for (int o = 0; o < HID; o += 4) {
        const uint2 h2 = *reinterpret_cast<const uint2*>(hps + i * HID + o);
        a = fmaf(pklo(h2.x), pW2[(o + 0) * NFT + f], a);
        a = fmaf(pkhi(h2.x), pW2[(o + 1) * NFT + f], a);
        a = fmaf(pklo(h2.y), pW2[(o + 2) * NFT + f], a);
        a = fmaf(pkhi(h2.y), pW2[(o + 3) * NFT + f], a);
      }
      o24[i * 25 + f] = a;
    }
    __syncthreads();

    // 4f: IDCT along the 24 coeffs + coalesced store (i fast -> consecutive addrs)
    for (int idx = tid; idx < TTA * NFT; idx += BDIM) {
      const int tt_ = idx / TTA, i = idx - tt_ * TTA;
      float a = 0.0f;
#pragma unroll
      for (int k = 0; k < NFT; ++k) a = fmaf(o24[i * 25 + k], mtab[k * NFT + tt_], a);
      out[(size_t)b * (NFT * TOK) + tt_ * TOK + (t0 + i)] = a;
    }
    __syncthreads();
  }
}

extern "C" void kernel_launch(void* const* d_in, const int* in_sizes, int n_in,
                              void* d_out, int out_size, void* d_ws, size_t ws_size,
                              hipStream_t stream)
{
  (void)in_sizes; (void)n_in; (void)out_size; (void)d_ws; (void)ws_size;

  const float* x   = (const float*)d_in[0];
  const float* qW1 = (const float*)d_in[1];
  const float* qb1 = (const float*)d_in[2];
  const float* qW2 = (const float*)d_in[3];
  const float* qb2 = (const float*)d_in[4];
  const float* kW1 = (const float*)d_in[5];
  const float* kb1 = (const float*)d_in[6];
  const float* kW2 = (const float*)d_in[7];
  const float* kb2 = (const float*)d_in[8];
  const float* vW1 = (const float*)d_in[9];
  const float* vb1 = (const float*)d_in[10];
  const float* vW2 = (const float*)d_in[11];
  const float* vb2 = (const float*)d_in[12];
  const float* pW1 = (const float*)d_in[13];
  const float* pb1 = (const float*)d_in[14];
  const float* pW2 = (const float*)d_in[15];
  const float* pb2 = (const float*)d_in[16];
  float* out = (float*)d_out;

  // >64KB dynamic LDS opt-in (capture-safe: not a stream op; errors ignored)
  (void)hipFuncSetAttribute((const void*)fused_motion_attn,
                            hipFuncAttributeMaxDynamicSharedMemorySize, SMEM_BYTES);

  fused_motion_attn<<<dim3(BATCH), dim3(BDIM), SMEM_BYTES, stream>>>(
      x, qW1, qb1, qW2, qb2, kW1, kb1, kW2, kb2,
      vW1, vb1, vW2, vb2, pW1, pb1, pW2, pb2, out);
}

// Round 2
// 817.206 us; speedup vs baseline: 13.7983x; 13.7983x over previous
//
#include <hip/hip_runtime.h>

#define BDIM 512

typedef float f32x4 __attribute__((ext_vector_type(4)));
typedef short bf16x8 __attribute__((ext_vector_type(8)));

#define MFMA(a, b, c) __builtin_amdgcn_mfma_f32_16x16x32_bf16((a), (b), (c), 0, 0, 0)

// ---- weight workspace layout (bf16 elements in d_ws) ----
// all matrices stored [N][K] row-major ("transposed"), zero-padded
constexpr int OQ1 = 0;                  // qW1t [256][32]  (k 20..31 = 0)
constexpr int OK1w = 8192;              // kW1t [256][32]
constexpr int OV1 = 16384;              // vW1t [256][32]
constexpr int OQ2 = 24576;              // qW2t [256][256]
constexpr int OK2w = 90112;             // kW2t [256][256]
constexpr int OV2 = 155648;             // vW2t [256][256]
constexpr int OP1 = 221184;             // pW1t [256][512]
constexpr int OP2 = 352256;             // pW2t [32][256]  (rows 24..31 = 0)
constexpr int WTOT = 360448;            // elements (720896 bytes)

// ---- LDS layout (bytes) ----
// Q   [144][256] bf16  persistent until p-L1
// XS  [160][32]  bf16  input (rows>=135, cols>=20 zero)
// SP  [144][144] bf16  scores/P in-place; same base reused as H (Q-MLP hidden),
//                      ctx, hp ([144][256] bf16, spans SP+HT2+KVT when those are dead)
// HT2 [32][256]  bf16  K/V-chunk layer-1 hidden tile
// KVT [32][256]  bf16  K-tile   /  Vt-tile [256][32] (transposed V chunk)
// RWL [144]      f32   softmax denominators
// O   [144][25]  f32   (over Q region, after Q dead) ; MT [24][24] f32 at +14400
constexpr int OFF_Q   = 0;
constexpr int OFF_XS  = 73728;
constexpr int OFF_SP  = 83968;
constexpr int OFF_HT2 = 125440;
constexpr int OFF_KVT = 141824;
constexpr int OFF_RWL = 158208;
constexpr int SMEM_BYTES = 158784;      // < 161824 proven grantable in R1

__device__ __forceinline__ unsigned short f2b(float f) {
  unsigned int u = __float_as_uint(f);
  return (unsigned short)((u + 0x7fffu + ((u >> 16) & 1u)) >> 16);
}
__device__ __forceinline__ float bfu(unsigned short u) {
  return __uint_as_float(((unsigned int)u) << 16);
}

// fragment load from row-major [.][strideElems] bf16 matrix (LDS or global):
// lane l reads 8 contiguous elements at row rb+(l&15), col kb+(l>>4)*8
__device__ __forceinline__ bf16x8 frag(const unsigned short* m, int rb, int stride,
                                       int kb, int lane) {
  return *(const bf16x8*)(m + (rb + (lane & 15)) * stride + kb + ((lane >> 4) << 3));
}

// ---------------- weight prep: f32 -> bf16, transposed, padded ----------------
__global__ void prep_w(const float* __restrict__ qW1, const float* __restrict__ qW2,
                       const float* __restrict__ kW1, const float* __restrict__ kW2,
                       const float* __restrict__ vW1, const float* __restrict__ vW2,
                       const float* __restrict__ pW1, const float* __restrict__ pW2,
                       unsigned short* __restrict__ ws) {
  int i = blockIdx.x * 256 + threadIdx.x;
  if (i >= WTOT) return;
  float v = 0.f;
  if (i < OQ2) {                       // W1t blocks [256][32]
    int sel = i >> 13, r = i & 8191;
    int o = r >> 5, k = r & 31;
    const float* W = (sel == 0) ? qW1 : (sel == 1) ? kW1 : vW1;
    if (k < 20) v = W[k * 256 + o];
  } else if (i < OP1) {                // W2t blocks [256][256]
    int r = i - OQ2;
    int sel = r >> 16, q = r & 65535;
    int o = q >> 8, k = q & 255;
    const float* W = (sel == 0) ? qW2 : (sel == 1) ? kW2 : vW2;
    v = W[k * 256 + o];
  } else if (i < OP2) {                // pW1t [256][512]
    int r = i - OP1;
    int o = r >> 9, f = r & 511;
    v = pW1[f * 256 + o];
  } else {                             // pW2t [32][256]
    int r = i - OP2;
    int o = r >> 8, k = r & 255;
    if (o < 24) v = pW2[k * 24 + o];
  }
  ws[i] = f2b(v);
}

// ---------------- fused main kernel: 1 block = 1 batch ----------------
__global__ __launch_bounds__(BDIM, 2)
void motion_mfma(const float* __restrict__ x,
                 const float* __restrict__ qb1v, const float* __restrict__ qb2v,
                 const float* __restrict__ kb1v, const float* __restrict__ kb2v,
                 const float* __restrict__ vb1v, const float* __restrict__ vb2v,
                 const float* __restrict__ pb1v, const float* __restrict__ pb2v,
                 const unsigned short* __restrict__ ws,
                 float* __restrict__ out) {
  extern __shared__ char smem[];
  unsigned short* Qs  = (unsigned short*)(smem + OFF_Q);
  unsigned short* XS  = (unsigned short*)(smem + OFF_XS);
  unsigned short* SP  = (unsigned short*)(smem + OFF_SP);
  unsigned short* Hc  = (unsigned short*)(smem + OFF_SP);   // H / ctx / hp
  unsigned short* HT2 = (unsigned short*)(smem + OFF_HT2);
  unsigned short* KVT = (unsigned short*)(smem + OFF_KVT);
  float* RWL = (float*)(smem + OFF_RWL);
  float* Ob  = (float*)(smem + 0);
  float* MT  = (float*)(smem + 14400);

  const int tid = threadIdx.x, lane = tid & 63, w = tid >> 6;
  const int l15 = lane & 15, rs = ((lane >> 4) << 2);
  const int cb = w * 32;               // wave's two 16-col n-tiles: cb, cb+16
  const int b = blockIdx.x;
  const f32x4 zf4 = {0.f, 0.f, 0.f, 0.f};
  const bf16x8 zb8 = {0, 0, 0, 0, 0, 0, 0, 0};

  // P0: stage x -> XS [160][32] bf16, zero-padded
  const float* xb = x + (size_t)b * 2700;
  for (int i = tid; i < 160 * 32; i += BDIM) {
    int r = i >> 5, c = i & 31;
    XS[i] = (r < 135 && c < 20) ? f2b(xb[r * 20 + c]) : (unsigned short)0;
  }
  __syncthreads();

  // ---------------- Q MLP (full H in arena) ----------------
  {
    bf16x8 w0 = frag(ws + OQ1, cb, 32, 0, lane);
    bf16x8 w1 = frag(ws + OQ1, cb + 16, 32, 0, lane);
    float bb0 = qb1v[cb + l15], bb1 = qb1v[cb + 16 + l15];
#pragma unroll
    for (int m = 0; m < 9; ++m) {
      bf16x8 a = frag(XS, m * 16, 32, 0, lane);
      f32x4 c0 = MFMA(a, w0, zf4);
      f32x4 c1 = MFMA(a, w1, zf4);
#pragma unroll
      for (int r = 0; r < 4; ++r) {
        Hc[(m * 16 + rs + r) * 256 + cb + l15]      = f2b(fmaxf(c0[r] + bb0, 0.f));
        Hc[(m * 16 + rs + r) * 256 + cb + 16 + l15] = f2b(fmaxf(c1[r] + bb1, 0.f));
      }
    }
    __syncthreads();

    f32x4 acc[9][2];
#pragma unroll
    for (int m = 0; m < 9; ++m) { acc[m][0] = zf4; acc[m][1] = zf4; }
    for (int ks = 0; ks < 8; ++ks) {
      bf16x8 g0 = frag(ws + OQ2, cb, 256, ks * 32, lane);
      bf16x8 g1 = frag(ws + OQ2, cb + 16, 256, ks * 32, lane);
#pragma unroll
      for (int m = 0; m < 9; ++m) {
        bf16x8 a = frag(Hc, m * 16, 256, ks * 32, lane);
        acc[m][0] = MFMA(a, g0, acc[m][0]);
        acc[m][1] = MFMA(a, g1, acc[m][1]);
      }
    }
    float bb20 = qb2v[cb + l15], bb21 = qb2v[cb + 16 + l15];
#pragma unroll
    for (int m = 0; m < 9; ++m)
#pragma unroll
      for (int r = 0; r < 4; ++r) {
        Qs[(m * 16 + rs + r) * 256 + cb + l15]      = f2b(acc[m][0][r] + bb20);
        Qs[(m * 16 + rs + r) * 256 + cb + 16 + l15] = f2b(acc[m][1][r] + bb21);
      }
  }
  __syncthreads();   // H reads done before HT2 (overlapping) is written

  // ---------------- K chunks (32 tokens) fused with scores ----------------
  for (int ch = 0; ch < 5; ++ch) {
    const int s0 = ch * 32;
    {  // L1 -> HT2
      bf16x8 w0 = frag(ws + OK1w, cb, 32, 0, lane);
      bf16x8 w1 = frag(ws + OK1w, cb + 16, 32, 0, lane);
      float bb0 = kb1v[cb + l15], bb1 = kb1v[cb + 16 + l15];
#pragma unroll
      for (int mm = 0; mm < 2; ++mm) {
        bf16x8 a = frag(XS, s0 + mm * 16, 32, 0, lane);
        f32x4 c0 = MFMA(a, w0, zf4), c1 = MFMA(a, w1, zf4);
#pragma unroll
        for (int r = 0; r < 4; ++r) {
          HT2[(mm * 16 + rs + r) * 256 + cb + l15]      = f2b(fmaxf(c0[r] + bb0, 0.f));
          HT2[(mm * 16 + rs + r) * 256 + cb + 16 + l15] = f2b(fmaxf(c1[r] + bb1, 0.f));
        }
      }
    }
    __syncthreads();
    {  // L2 -> Ktile [32][256]
      f32x4 a2[2][2] = {{zf4, zf4}, {zf4, zf4}};
      for (int ks = 0; ks < 8; ++ks) {
        bf16x8 g0 = frag(ws + OK2w, cb, 256, ks * 32, lane);
        bf16x8 g1 = frag(ws + OK2w, cb + 16, 256, ks * 32, lane);
#pragma unroll
        for (int mm = 0; mm < 2; ++mm) {
          bf16x8 a = frag(HT2, mm * 16, 256, ks * 32, lane);
          a2[mm][0] = MFMA(a, g0, a2[mm][0]);
          a2[mm][1] = MFMA(a, g1, a2[mm][1]);
        }
      }
      float bb0 = kb2v[cb + l15], bb1 = kb2v[cb + 16 + l15];
#pragma unroll
      for (int mm = 0; mm < 2; ++mm)
#pragma unroll
        for (int r = 0; r < 4; ++r) {
          KVT[(mm * 16 + rs + r) * 256 + cb + l15]      = f2b(a2[mm][0][r] + bb0);
          KVT[(mm * 16 + rs + r) * 256 + cb + 16 + l15] = f2b(a2[mm][1][r] + bb1);
        }
    }
    __syncthreads();
    // scores slab: S[:, s0..s0+31] = Q @ Ktile^T / 16 ; jobs j = m*2+n
#pragma unroll
    for (int rep = 0; rep < 3; ++rep) {
      int j = w + rep * 8;
      if (j < 18) {
        int m = j >> 1, n = j & 1;
        int sb = s0 + n * 16;
        if (sb < 144) {
          f32x4 sa = zf4;
          for (int ks = 0; ks < 8; ++ks) {
            bf16x8 qa = frag(Qs, m * 16, 256, ks * 32, lane);
            bf16x8 kf = frag(KVT, n * 16, 256, ks * 32, lane);
            sa = MFMA(qa, kf, sa);
          }
#pragma unroll
          for (int r = 0; r < 4; ++r)
            SP[(m * 16 + rs + r) * 144 + sb + l15] = f2b(sa[r] * 0.0625f);
        }
      }
    }
    __syncthreads();
  }

  // ---------------- softmax in-place (mask s>=135), denom -> RWL ----------------
#pragma unroll
  for (int pass = 0; pass < 2; ++pass) {
    int r = pass * 128 + (tid >> 2);
    if (r < 144) {
      int j = tid & 3;
      float mx = -1e30f;
      for (int s = j; s < 135; s += 4) mx = fmaxf(mx, bfu(SP[r * 144 + s]));
      mx = fmaxf(mx, __shfl_xor(mx, 1));
      mx = fmaxf(mx, __shfl_xor(mx, 2));
      float sum = 0.f;
      for (int s = j; s < 135; s += 4) {
        float p = __expf(bfu(SP[r * 144 + s]) - mx);
        SP[r * 144 + s] = f2b(p);
        sum += p;
      }
      sum += __shfl_xor(sum, 1);
      sum += __shfl_xor(sum, 2);
      if (j == 0) RWL[r] = sum;
      for (int s = 135 + j; s < 144; s += 4) SP[r * 144 + s] = 0;
    }
  }
  __syncthreads();

  // ---------------- V chunks fused with context (ctx acc in regs) ----------------
  f32x4 ctx[9][2];
#pragma unroll
  for (int m = 0; m < 9; ++m) { ctx[m][0] = zf4; ctx[m][1] = zf4; }
  for (int ch = 0; ch < 5; ++ch) {
    const int s0 = ch * 32;
    {  // L1 -> HT2
      bf16x8 w0 = frag(ws + OV1, cb, 32, 0, lane);
      bf16x8 w1 = frag(ws + OV1, cb + 16, 32, 0, lane);
      float bb0 = vb1v[cb + l15], bb1 = vb1v[cb + 16 + l15];
#pragma unroll
      for (int mm = 0; mm < 2; ++mm) {
        bf16x8 a = frag(XS, s0 + mm * 16, 32, 0, lane);
        f32x4 c0 = MFMA(a, w0, zf4), c1 = MFMA(a, w1, zf4);
#pragma unroll
        for (int r = 0; r < 4; ++r) {
          HT2[(mm * 16 + rs + r) * 256 + cb + l15]      = f2b(fmaxf(c0[r] + bb0, 0.f));
          HT2[(mm * 16 + rs + r) * 256 + cb + 16 + l15] = f2b(fmaxf(c1[r] + bb1, 0.f));
        }
      }
    }
    __syncthreads();
    {  // L2 -> Vt_tile [256][32] (transposed write)
      f32x4 a2[2][2] = {{zf4, zf4}, {zf4, zf4}};
      for (int ks = 0; ks < 8; ++ks) {
        bf16x8 g0 = frag(ws + OV2, cb, 256, ks * 32, lane);
        bf16x8 g1 = frag(ws + OV2, cb + 16, 256, ks * 32, lane);
#pragma unroll
        for (int mm = 0; mm < 2; ++mm) {
          bf16x8 a = frag(HT2, mm * 16, 256, ks * 32, lane);
          a2[mm][0] = MFMA(a, g0, a2[mm][0]);
          a2[mm][1] = MFMA(a, g1, a2[mm][1]);
        }
      }
      float bb0 = vb2v[cb + l15], bb1 = vb2v[cb + 16 + l15];
#pragma unroll
      for (int mm = 0; mm < 2; ++mm)
#pragma unroll
        for (int r = 0; r < 4; ++r) {
          KVT[(cb + l15) * 32      + mm * 16 + rs + r] = f2b(a2[mm][0][r] + bb0);
          KVT[(cb + 16 + l15) * 32 + mm * 16 + rs + r] = f2b(a2[mm][1][r] + bb1);
        }
    }
    __syncthreads();
    {  // context k-step: ctx += P[:, s0..s0+31] @ V[s0..s0+31, :]
      bf16x8 v0 = frag(KVT, cb, 32, 0, lane);
      bf16x8 v1 = frag(KVT, cb + 16, 32, 0, lane);
      const bool mask = (ch == 4) && (lane >= 32);   // s >= 144 lanes
#pragma unroll
      for (int m = 0; m < 9; ++m) {
        bf16x8 pa = frag(SP, m * 16, 144, s0, lane);
        if (mask) pa = zb8;
        ctx[m][0] = MFMA(pa, v0, ctx[m][0]);
        ctx[m][1] = MFMA(pa, v1, ctx[m][1]);
      }
    }
    // next-iter L1 writes HT2 only; its barrier orders KVT/SP reuse
  }
  __syncthreads();   // all SP/KVT reads done before ctx overwrites arena

  // normalize + write ctx (bf16) into Hc
#pragma unroll
  for (int m = 0; m < 9; ++m)
#pragma unroll
    for (int r = 0; r < 4; ++r) {
      int t = m * 16 + rs + r;
      float inv = 1.0f / RWL[t];
      Hc[t * 256 + cb + l15]      = f2b(ctx[m][0][r] * inv);
      Hc[t * 256 + cb + 16 + l15] = f2b(ctx[m][1][r] * inv);
    }
  __syncthreads();

  // ---------------- p-L1: hp = relu([Q | ctx] @ pW1 + pb1) ----------------
  {
    float pbias0 = pb1v[cb + l15], pbias1 = pb1v[cb + 16 + l15];
    f32x4 pacc[9][2];
#pragma unroll
    for (int m = 0; m < 9; ++m) {
      pacc[m][0] = (f32x4){pbias0, pbias0, pbias0, pbias0};
      pacc[m][1] = (f32x4){pbias1, pbias1, pbias1, pbias1};
    }
    for (int ks = 0; ks < 16; ++ks) {
      bf16x8 g0 = frag(ws + OP1, cb, 512, ks * 32, lane);
      bf16x8 g1 = frag(ws + OP1, cb + 16, 512, ks * 32, lane);
      const unsigned short* As = (ks < 8) ? Qs : Hc;
      int kk = (ks & 7) * 32;
#pragma unroll
      for (int m = 0; m < 9; ++m) {
        bf16x8 a = frag(As, m * 16, 256, kk, lane);
        pacc[m][0] = MFMA(a, g0, pacc[m][0]);
        pacc[m][1] = MFMA(a, g1, pacc[m][1]);
      }
    }
    __syncthreads();   // Q/ctx reads done by ALL waves before hp/MT overwrite
#pragma unroll
    for (int m = 0; m < 9; ++m)
#pragma unroll
      for (int r = 0; r < 4; ++r) {
        Hc[(m * 16 + rs + r) * 256 + cb + l15]      = f2b(fmaxf(pacc[m][0][r], 0.f));
        Hc[(m * 16 + rs + r) * 256 + cb + 16 + l15] = f2b(fmaxf(pacc[m][1][r], 0.f));
      }
  }
  // IDCT basis into MT (Q region is dead)
  for (int i = tid; i < 576; i += BDIM) {
    int kk = i / 24, t = i - kk * 24;
    float c = (kk == 0) ? 0.20412414523193150f : 0.28867513459481287f;
    MT[i] = c * cosf(0.065449846949787352f * (float)(kk * (2 * t + 1)));
  }
  __syncthreads();

  // ---------------- p-L2: o = hp @ pW2 + pb2 -> Ob [144][25] f32 ----------------
#pragma unroll
  for (int rep = 0; rep < 3; ++rep) {
    int j = w + rep * 8;
    if (j < 18) {
      int m = j >> 1, n = j & 1;
      f32x4 oa = zf4;
      for (int ks = 0; ks < 8; ++ks) {
        bf16x8 a = frag(Hc, m * 16, 256, ks * 32, lane);
        bf16x8 g = frag(ws + OP2, n * 16, 256, ks * 32, lane);
        oa = MFMA(a, g, oa);
      }
      int c = n * 16 + l15;
      if (c < 24) {
        float bb = pb2v[c];
#pragma unroll
        for (int r = 0; r < 4; ++r)
          Ob[(m * 16 + rs + r) * 25 + c] = oa[r] + bb;
      }
    }
  }
  __syncthreads();

  // ---------------- IDCT + coalesced store ----------------
  for (int i = tid; i < 3240; i += BDIM) {
    int tt = i / 135, tok = i - tt * 135;
    float a = 0.f;
#pragma unroll
    for (int k = 0; k < 24; ++k)
      a = fmaf(Ob[tok * 25 + k], MT[k * 24 + tt], a);
    out[(size_t)b * 3240 + i] = a;
  }
}

extern "C" void kernel_launch(void* const* d_in, const int* in_sizes, int n_in,
                              void* d_out, int out_size, void* d_ws, size_t ws_size,
                              hipStream_t stream) {
  (void)in_sizes; (void)n_in; (void)out_size;
  if (ws_size < (size_t)WTOT * 2) return;   // workspace too small -> fail loudly

  const float* x   = (const float*)d_in[0];
  const float* qW1 = (const float*)d_in[1];
  const float* qb1 = (const float*)d_in[2];
  const float* qW2 = (const float*)d_in[3];
  const float* qb2 = (const float*)d_in[4];
  const float* kW1 = (const float*)d_in[5];
  const float* kb1 = (const float*)d_in[6];
  const float* kW2 = (const float*)d_in[7];
  const float* kb2 = (const float*)d_in[8];
  const float* vW1 = (const float*)d_in[9];
  const float* vb1 = (const float*)d_in[10];
  const float* vW2 = (const float*)d_in[11];
  const float* vb2 = (const float*)d_in[12];
  const float* pW1 = (const float*)d_in[13];
  const float* pb1 = (const float*)d_in[14];
  const float* pW2 = (const float*)d_in[15];
  const float* pb2 = (const float*)d_in[16];
  float* out = (float*)d_out;
  unsigned short* ws = (unsigned short*)d_ws;

  prep_w<<<dim3((WTOT + 255) / 256), dim3(256), 0, stream>>>(
      qW1, qW2, kW1, kW2, vW1, vW2, pW1, pW2, ws);

  (void)hipFuncSetAttribute((const void*)motion_mfma,
                            hipFuncAttributeMaxDynamicSharedMemorySize, SMEM_BYTES);
  motion_mfma<<<dim3(2048), dim3(BDIM), SMEM_BYTES, stream>>>(
      x, qb1, qb2, kb1, kb2, vb1, vb2, pb1, pb2, ws, out);
}

// Round 3
// 603.228 us; speedup vs baseline: 18.6928x; 1.3547x over previous
//
#include <hip/hip_runtime.h>

#define BDIM 512

typedef float f32x4 __attribute__((ext_vector_type(4)));
typedef short bf16x8 __attribute__((ext_vector_type(8)));

#define MFMA(a, b, c) __builtin_amdgcn_mfma_f32_16x16x32_bf16((a), (b), (c), 0, 0, 0)

// ---- weight workspace layout (bf16 elements in d_ws) ----
// all matrices stored [N][K] row-major ("transposed"), zero-padded
constexpr int OQ1 = 0;                  // qW1t [256][32]  (k 20..31 = 0)
constexpr int OK1w = 8192;              // kW1t [256][32]
constexpr int OV1 = 16384;              // vW1t [256][32]
constexpr int OQ2 = 24576;              // qW2t [256][256]
constexpr int OK2w = 90112;             // kW2t [256][256]
constexpr int OV2 = 155648;             // vW2t [256][256]
constexpr int OP1 = 221184;             // pW1t [256][512]
constexpr int OP2 = 352256;             // pW2t [32][256]  (rows 24..31 = 0)
constexpr int WTOT = 360448;            // elements (720896 bytes)

// ---- LDS layout (bytes) ----
// Q   [144][256] bf16 swizzled(row&7)     persistent until p-L1
// XS  [160][32]  bf16 swizzled((r>>1)&3)  input
// SP  [144][152] bf16 plain (stride-152 spreads banks); + OOB-read slack
// Hc  arena [144][256] swizzled, overlays SP..KVT when those are dead
// HT2 [32][256]  bf16 swizzled            K/V L1 hidden tile
// KVT [32][256] swizzled (K-tile)  /  [256][32] swizzled32 (Vt-tile)
// RWL [144] f32 softmax denoms
// Ob  [144][25] f32 over dead Q; MT [24][24] f32 at +14400
constexpr int OFF_Q   = 0;
constexpr int OFF_XS  = 73728;
constexpr int OFF_SP  = 83968;          // 43808 bytes incl. masked-read slack
constexpr int OFF_HT2 = 127776;
constexpr int OFF_KVT = 144160;
constexpr int OFF_RWL = 160544;
constexpr int SMEM_BYTES = 161120;      // <= 161824 proven grantable in R1

constexpr int SPS = 152;                // SP row stride (elements)

__device__ __forceinline__ unsigned short f2b(float f) {
  unsigned int u = __float_as_uint(f);
  return (unsigned short)((u + 0x7fffu + ((u >> 16) & 1u)) >> 16);
}
__device__ __forceinline__ float bfu(unsigned short u) {
  return __uint_as_float(((unsigned int)u) << 16);
}

// plain fragment load (global weights, SP): lane l -> row rb+(l&15), col kb+(l>>4)*8
__device__ __forceinline__ bf16x8 frag(const unsigned short* m, int rb, int stride,
                                       int kb, int lane) {
  return *(const bf16x8*)(m + (rb + (lane & 15)) * stride + kb + ((lane >> 4) << 3));
}
// swizzled fragment load, stride-256 LDS tiles
__device__ __forceinline__ bf16x8 frag256s(const unsigned short* m, int rb, int kb, int lane) {
  const int row = rb + (lane & 15);
  const int c = (kb + ((lane >> 4) << 3)) ^ ((row & 7) << 3);
  return *(const bf16x8*)(m + row * 256 + c);
}
// swizzled fragment load, stride-32 LDS tiles (kb==0 always)
__device__ __forceinline__ bf16x8 frag32s(const unsigned short* m, int rb, int lane) {
  const int row = rb + (lane & 15);
  const int c = ((lane >> 4) << 3) ^ (((row >> 1) & 3) << 3);
  return *(const bf16x8*)(m + row * 32 + c);
}
// swizzled scalar-store index helpers (must match the frag*s formulas)
__device__ __forceinline__ int swz256(int r, int c) { return r * 256 + (c ^ ((r & 7) << 3)); }
__device__ __forceinline__ int swz32 (int r, int c) { return r * 32  + (c ^ (((r >> 1) & 3) << 3)); }

// ---------------- weight prep: f32 -> bf16, transposed, padded ----------------
__global__ void prep_w(const float* __restrict__ qW1, const float* __restrict__ qW2,
                       const float* __restrict__ kW1, const float* __restrict__ kW2,
                       const float* __restrict__ vW1, const float* __restrict__ vW2,
                       const float* __restrict__ pW1, const float* __restrict__ pW2,
                       unsigned short* __restrict__ ws) {
  int i = blockIdx.x * 256 + threadIdx.x;
  if (i >= WTOT) return;
  float v = 0.f;
  if (i < OQ2) {                       // W1t blocks [256][32]
    int sel = i >> 13, r = i & 8191;
    int o = r >> 5, k = r & 31;
    const float* W = (sel == 0) ? qW1 : (sel == 1) ? kW1 : vW1;
    if (k < 20) v = W[k * 256 + o];
  } else if (i < OP1) {                // W2t blocks [256][256]
    int r = i - OQ2;
    int sel = r >> 16, q = r & 65535;
    int o = q >> 8, k = q & 255;
    const float* W = (sel == 0) ? qW2 : (sel == 1) ? kW2 : vW2;
    v = W[k * 256 + o];
  } else if (i < OP2) {                // pW1t [256][512]
    int r = i - OP1;
    int o = r >> 9, f = r & 511;
    v = pW1[f * 256 + o];
  } else {                             // pW2t [32][256]
    int r = i - OP2;
    int o = r >> 8, k = r & 255;
    if (o < 24) v = pW2[k * 24 + o];
  }
  ws[i] = f2b(v);
}

// ---------------- fused main kernel: 1 block = 1 batch ----------------
__global__ __launch_bounds__(BDIM, 2)
void motion_mfma(const float* __restrict__ x,
                 const float* __restrict__ qb1v, const float* __restrict__ qb2v,
                 const float* __restrict__ kb1v, const float* __restrict__ kb2v,
                 const float* __restrict__ vb1v, const float* __restrict__ vb2v,
                 const float* __restrict__ pb1v, const float* __restrict__ pb2v,
                 const unsigned short* __restrict__ ws,
                 float* __restrict__ out) {
  extern __shared__ char smem[];
  unsigned short* Qs  = (unsigned short*)(smem + OFF_Q);
  unsigned short* XS  = (unsigned short*)(smem + OFF_XS);
  unsigned short* SP  = (unsigned short*)(smem + OFF_SP);
  unsigned short* Hc  = (unsigned short*)(smem + OFF_SP);   // H / ctx / hp arena
  unsigned short* HT2 = (unsigned short*)(smem + OFF_HT2);
  unsigned short* KVT = (unsigned short*)(smem + OFF_KVT);
  float* RWL = (float*)(smem + OFF_RWL);
  float* Ob  = (float*)(smem + 0);
  float* MT  = (float*)(smem + 14400);

  const int tid = threadIdx.x, lane = tid & 63, w = tid >> 6;
  const int l15 = lane & 15, rs = ((lane >> 4) << 2);
  const int cb = w * 32;               // wave's two 16-col n-tiles: cb, cb+16
  const int b = blockIdx.x;
  const f32x4 zf4 = {0.f, 0.f, 0.f, 0.f};
  const bf16x8 zb8 = {0, 0, 0, 0, 0, 0, 0, 0};

  // P0: stage x -> XS [160][32] bf16 (swizzled32), zero-padded
  const float* xb = x + (size_t)b * 2700;
  for (int i = tid; i < 160 * 32; i += BDIM) {
    int r = i >> 5, c = i & 31;
    XS[swz32(r, c)] = (r < 135 && c < 20) ? f2b(xb[r * 20 + c]) : (unsigned short)0;
  }
  __syncthreads();

  // ---------------- Q MLP (full H in arena) ----------------
  {
    bf16x8 w0 = frag(ws + OQ1, cb, 32, 0, lane);
    bf16x8 w1 = frag(ws + OQ1, cb + 16, 32, 0, lane);
    float bb0 = qb1v[cb + l15], bb1 = qb1v[cb + 16 + l15];
#pragma unroll
    for (int m = 0; m < 9; ++m) {
      bf16x8 a = frag32s(XS, m * 16, lane);
      f32x4 c0 = MFMA(a, w0, zf4);
      f32x4 c1 = MFMA(a, w1, zf4);
#pragma unroll
      for (int r = 0; r < 4; ++r) {
        Hc[swz256(m * 16 + rs + r, cb + l15)]      = f2b(fmaxf(c0[r] + bb0, 0.f));
        Hc[swz256(m * 16 + rs + r, cb + 16 + l15)] = f2b(fmaxf(c1[r] + bb1, 0.f));
      }
    }
    __syncthreads();

    f32x4 acc[9][2];
#pragma unroll
    for (int m = 0; m < 9; ++m) { acc[m][0] = zf4; acc[m][1] = zf4; }
    for (int ks = 0; ks < 8; ++ks) {
      bf16x8 g0 = frag(ws + OQ2, cb, 256, ks * 32, lane);
      bf16x8 g1 = frag(ws + OQ2, cb + 16, 256, ks * 32, lane);
#pragma unroll
      for (int m = 0; m < 9; ++m) {
        bf16x8 a = frag256s(Hc, m * 16, ks * 32, lane);
        acc[m][0] = MFMA(a, g0, acc[m][0]);
        acc[m][1] = MFMA(a, g1, acc[m][1]);
      }
    }
    float bb20 = qb2v[cb + l15], bb21 = qb2v[cb + 16 + l15];
#pragma unroll
    for (int m = 0; m < 9; ++m)
#pragma unroll
      for (int r = 0; r < 4; ++r) {
        Qs[swz256(m * 16 + rs + r, cb + l15)]      = f2b(acc[m][0][r] + bb20);
        Qs[swz256(m * 16 + rs + r, cb + 16 + l15)] = f2b(acc[m][1][r] + bb21);
      }
  }
  __syncthreads();   // H reads done before HT2 (overlapping) is written

  // ---------------- K chunks (32 tokens) fused with scores ----------------
  for (int ch = 0; ch < 5; ++ch) {
    const int s0 = ch * 32;
    {  // L1 -> HT2
      bf16x8 w0 = frag(ws + OK1w, cb, 32, 0, lane);
      bf16x8 w1 = frag(ws + OK1w, cb + 16, 32, 0, lane);
      float bb0 = kb1v[cb + l15], bb1 = kb1v[cb + 16 + l15];
#pragma unroll
      for (int mm = 0; mm < 2; ++mm) {
        bf16x8 a = frag32s(XS, s0 + mm * 16, lane);
        f32x4 c0 = MFMA(a, w0, zf4), c1 = MFMA(a, w1, zf4);
#pragma unroll
        for (int r = 0; r < 4; ++r) {
          HT2[swz256(mm * 16 + rs + r, cb + l15)]      = f2b(fmaxf(c0[r] + bb0, 0.f));
          HT2[swz256(mm * 16 + rs + r, cb + 16 + l15)] = f2b(fmaxf(c1[r] + bb1, 0.f));
        }
      }
    }
    __syncthreads();
    {  // L2 -> Ktile [32][256]
      f32x4 a2[2][2] = {{zf4, zf4}, {zf4, zf4}};
      for (int ks = 0; ks < 8; ++ks) {
        bf16x8 g0 = frag(ws + OK2w, cb, 256, ks * 32, lane);
        bf16x8 g1 = frag(ws + OK2w, cb + 16, 256, ks * 32, lane);
#pragma unroll
        for (int mm = 0; mm < 2; ++mm) {
          bf16x8 a = frag256s(HT2, mm * 16, ks * 32, lane);
          a2[mm][0] = MFMA(a, g0, a2[mm][0]);
          a2[mm][1] = MFMA(a, g1, a2[mm][1]);
        }
      }
      float bb0 = kb2v[cb + l15], bb1 = kb2v[cb + 16 + l15];
#pragma unroll
      for (int mm = 0; mm < 2; ++mm)
#pragma unroll
        for (int r = 0; r < 4; ++r) {
          KVT[swz256(mm * 16 + rs + r, cb + l15)]      = f2b(a2[mm][0][r] + bb0);
          KVT[swz256(mm * 16 + rs + r, cb + 16 + l15)] = f2b(a2[mm][1][r] + bb1);
        }
    }
    __syncthreads();
    // scores slab: S[:, s0..s0+31] = Q @ Ktile^T / 16 ; jobs j = m*2+n
#pragma unroll
    for (int rep = 0; rep < 3; ++rep) {
      int j = w + rep * 8;
      if (j < 18) {
        int m = j >> 1, n = j & 1;
        int sb = s0 + n * 16;
        if (sb < 144) {
          f32x4 sa = zf4;
          for (int ks = 0; ks < 8; ++ks) {
            bf16x8 qa = frag256s(Qs, m * 16, ks * 32, lane);
            bf16x8 kf = frag256s(KVT, n * 16, ks * 32, lane);
            sa = MFMA(qa, kf, sa);
          }
#pragma unroll
          for (int r = 0; r < 4; ++r)
            SP[(m * 16 + rs + r) * SPS + sb + l15] = f2b(sa[r] * 0.0625f);
        }
      }
    }
    __syncthreads();
  }

  // ---------------- softmax in-place (mask s>=135), denom -> RWL ----------------
#pragma unroll
  for (int pass = 0; pass < 2; ++pass) {
    int r = pass * 128 + (tid >> 2);
    if (r < 144) {
      int j = tid & 3;
      float mx = -1e30f;
      for (int s = j; s < 135; s += 4) mx = fmaxf(mx, bfu(SP[r * SPS + s]));
      mx = fmaxf(mx, __shfl_xor(mx, 1));
      mx = fmaxf(mx, __shfl_xor(mx, 2));
      float sum = 0.f;
      for (int s = j; s < 135; s += 4) {
        float p = __expf(bfu(SP[r * SPS + s]) - mx);
        SP[r * SPS + s] = f2b(p);
        sum += p;
      }
      sum += __shfl_xor(sum, 1);
      sum += __shfl_xor(sum, 2);
      if (j == 0) RWL[r] = sum;
      for (int s = 135 + j; s < 144; s += 4) SP[r * SPS + s] = 0;
    }
  }
  __syncthreads();

  // ---------------- V chunks fused with context (ctx acc in regs) ----------------
  f32x4 ctx[9][2];
#pragma unroll
  for (int m = 0; m < 9; ++m) { ctx[m][0] = zf4; ctx[m][1] = zf4; }
  for (int ch = 0; ch < 5; ++ch) {
    const int s0 = ch * 32;
    {  // L1 -> HT2
      bf16x8 w0 = frag(ws + OV1, cb, 32, 0, lane);
      bf16x8 w1 = frag(ws + OV1, cb + 16, 32, 0, lane);
      float bb0 = vb1v[cb + l15], bb1 = vb1v[cb + 16 + l15];
#pragma unroll
      for (int mm = 0; mm < 2; ++mm) {
        bf16x8 a = frag32s(XS, s0 + mm * 16, lane);
        f32x4 c0 = MFMA(a, w0, zf4), c1 = MFMA(a, w1, zf4);
#pragma unroll
        for (int r = 0; r < 4; ++r) {
          HT2[swz256(mm * 16 + rs + r, cb + l15)]      = f2b(fmaxf(c0[r] + bb0, 0.f));
          HT2[swz256(mm * 16 + rs + r, cb + 16 + l15)] = f2b(fmaxf(c1[r] + bb1, 0.f));
        }
      }
    }
    __syncthreads();
    {  // L2 -> Vt_tile [256][32] swizzled32 (transposed write)
      f32x4 a2[2][2] = {{zf4, zf4}, {zf4, zf4}};
      for (int ks = 0; ks < 8; ++ks) {
        bf16x8 g0 = frag(ws + OV2, cb, 256, ks * 32, lane);
        bf16x8 g1 = frag(ws + OV2, cb + 16, 256, ks * 32, lane);
#pragma unroll
        for (int mm = 0; mm < 2; ++mm) {
          bf16x8 a = frag256s(HT2, mm * 16, ks * 32, lane);
          a2[mm][0] = MFMA(a, g0, a2[mm][0]);
          a2[mm][1] = MFMA(a, g1, a2[mm][1]);
        }
      }
      float bb0 = vb2v[cb + l15], bb1 = vb2v[cb + 16 + l15];
#pragma unroll
      for (int mm = 0; mm < 2; ++mm)
#pragma unroll
        for (int r = 0; r < 4; ++r) {
          KVT[swz32(cb + l15,      mm * 16 + rs + r)] = f2b(a2[mm][0][r] + bb0);
          KVT[swz32(cb + 16 + l15, mm * 16 + rs + r)] = f2b(a2[mm][1][r] + bb1);
        }
    }
    __syncthreads();
    {  // context k-step: ctx += P[:, s0..s0+31] @ V[s0..s0+31, :]
      bf16x8 v0 = frag32s(KVT, cb, lane);
      bf16x8 v1 = frag32s(KVT, cb + 16, lane);
      const bool mask = (ch == 4) && (lane >= 32);   // tokens >= 144
#pragma unroll
      for (int m = 0; m < 9; ++m) {
        bf16x8 pa = frag(SP, m * 16, SPS, s0, lane);
        if (mask) pa = zb8;
        ctx[m][0] = MFMA(pa, v0, ctx[m][0]);
        ctx[m][1] = MFMA(pa, v1, ctx[m][1]);
      }
    }
    // next-iter L1 barrier orders KVT/SP reuse
  }
  __syncthreads();   // all SP/KVT reads done before ctx overwrites arena

  // normalize + write ctx (bf16) into Hc
#pragma unroll
  for (int m = 0; m < 9; ++m)
#pragma unroll
    for (int r = 0; r < 4; ++r) {
      int t = m * 16 + rs + r;
      float inv = 1.0f / RWL[t];
      Hc[swz256(t, cb + l15)]      = f2b(ctx[m][0][r] * inv);
      Hc[swz256(t, cb + 16 + l15)] = f2b(ctx[m][1][r] * inv);
    }
  __syncthreads();

  // ---------------- p-L1: hp = relu([Q | ctx] @ pW1 + pb1) ----------------
  {
    float pbias0 = pb1v[cb + l15], pbias1 = pb1v[cb + 16 + l15];
    f32x4 pacc[9][2];
#pragma unroll
    for (int m = 0; m < 9; ++m) {
      pacc[m][0] = (f32x4){pbias0, pbias0, pbias0, pbias0};
      pacc[m][1] = (f32x4){pbias1, pbias1, pbias1, pbias1};
    }
    for (int ks = 0; ks < 16; ++ks) {
      bf16x8 g0 = frag(ws + OP1, cb, 512, ks * 32, lane);
      bf16x8 g1 = frag(ws + OP1, cb + 16, 512, ks * 32, lane);
      const unsigned short* As = (ks < 8) ? Qs : Hc;
      int kk = (ks & 7) * 32;
#pragma unroll
      for (int m = 0; m < 9; ++m) {
        bf16x8 a = frag256s(As, m * 16, kk, lane);
        pacc[m][0] = MFMA(a, g0, pacc[m][0]);
        pacc[m][1] = MFMA(a, g1, pacc[m][1]);
      }
    }
    __syncthreads();   // Q/ctx reads done by ALL waves before hp/MT overwrite
#pragma unroll
    for (int m = 0; m < 9; ++m)
#pragma unroll
      for (int r = 0; r < 4; ++r) {
        Hc[swz256(m * 16 + rs + r, cb + l15)]      = f2b(fmaxf(pacc[m][0][r], 0.f));
        Hc[swz256(m * 16 + rs + r, cb + 16 + l15)] = f2b(fmaxf(pacc[m][1][r], 0.f));
      }
  }
  // IDCT basis into MT (Q region is dead)
  for (int i = tid; i < 576; i += BDIM) {
    int kk = i / 24, t = i - kk * 24;
    float c = (kk == 0) ? 0.20412414523193150f : 0.28867513459481287f;
    MT[i] = c * cosf(0.065449846949787352f * (float)(kk * (2 * t + 1)));
  }
  __syncthreads();

  // ---------------- p-L2: o = hp @ pW2 + pb2 -> Ob [144][25] f32 ----------------
#pragma unroll
  for (int rep = 0; rep < 3; ++rep) {
    int j = w + rep * 8;
    if (j < 18) {
      int m = j >> 1, n = j & 1;
      f32x4 oa = zf4;
      for (int ks = 0; ks < 8; ++ks) {
        bf16x8 a = frag256s(Hc, m * 16, ks * 32, lane);
        bf16x8 g = frag(ws + OP2, n * 16, 256, ks * 32, lane);
        oa = MFMA(a, g, oa);
      }
      int c = n * 16 + l15;
      if (c < 24) {
        float bb = pb2v[c];
#pragma unroll
        for (int r = 0; r < 4; ++r)
          Ob[(m * 16 + rs + r) * 25 + c] = oa[r] + bb;
      }
    }
  }
  __syncthreads();

  // ---------------- IDCT + coalesced store ----------------
  for (int i = tid; i < 3240; i += BDIM) {
    int tt = i / 135, tok = i - tt * 135;
    float a = 0.f;
#pragma unroll
    for (int k = 0; k < 24; ++k)
      a = fmaf(Ob[tok * 25 + k], MT[k * 24 + tt], a);
    out[(size_t)b * 3240 + i] = a;
  }
}

extern "C" void kernel_launch(void* const* d_in, const int* in_sizes, int n_in,
                              void* d_out, int out_size, void* d_ws, size_t ws_size,
                              hipStream_t stream) {
  (void)in_sizes; (void)n_in; (void)out_size;
  if (ws_size < (size_t)WTOT * 2) return;   // workspace too small -> fail loudly

  const float* x   = (const float*)d_in[0];
  const float* qW1 = (const float*)d_in[1];
  const float* qb1 = (const float*)d_in[2];
  const float* qW2 = (const float*)d_in[3];
  const float* qb2 = (const float*)d_in[4];
  const float* kW1 = (const float*)d_in[5];
  const float* kb1 = (const float*)d_in[6];
  const float* kW2 = (const float*)d_in[7];
  const float* kb2 = (const float*)d_in[8];
  const float* vW1 = (const float*)d_in[9];
  const float* vb1 = (const float*)d_in[10];
  const float* vW2 = (const float*)d_in[11];
  const float* vb2 = (const float*)d_in[12];
  const float* pW1 = (const float*)d_in[13];
  const float* pb1 = (const float*)d_in[14];
  const float* pW2 = (const float*)d_in[15];
  const float* pb2 = (const float*)d_in[16];
  float* out = (float*)d_out;
  unsigned short* ws = (unsigned short*)d_ws;

  prep_w<<<dim3((WTOT + 255) / 256), dim3(256), 0, stream>>>(
      qW1, qW2, kW1, kW2, vW1, vW2, pW1, pW2, ws);

  (void)hipFuncSetAttribute((const void*)motion_mfma,
                            hipFuncAttributeMaxDynamicSharedMemorySize, SMEM_BYTES);
  motion_mfma<<<dim3(2048), dim3(BDIM), SMEM_BYTES, stream>>>(
      x, qb1, qb2, kb1, kb2, vb1, vb2, pb1, pb2, ws, out);
}